// Round 1
// 609.106 us; speedup vs baseline: 1.0455x; 1.0455x over previous
//
#include <hip/hip_runtime.h>
#include <hip/hip_bf16.h>

#define SEQ 2048
#define DM 2048
#define NH 16
#define HD 128
#define FF 8192

typedef float f4v __attribute__((ext_vector_type(4)));
typedef short s8v __attribute__((ext_vector_type(8)));

__device__ __forceinline__ ushort f2bf(float f) {
  unsigned int x = __float_as_uint(f);
  unsigned int r = (x + 0x7FFFu + ((x >> 16) & 1u)) >> 16;
  return (ushort)r;
}

#define AS1 __attribute__((address_space(1)))
#define AS3 __attribute__((address_space(3)))
__device__ __forceinline__ void load16_lds(const ushort* g, ushort* l) {
  __builtin_amdgcn_global_load_lds((const AS1 unsigned int*)g, (AS3 unsigned int*)l, 16, 0, 0);
}

// ---------------- fp32 -> bf16 convert ----------------
__global__ __launch_bounds__(256) void k_cvt(const float* __restrict__ in,
                                             ushort* __restrict__ out, int n4) {
  int i = blockIdx.x * 256 + threadIdx.x;
  if (i >= n4) return;
  f4v v = reinterpret_cast<const f4v*>(in)[i];
  ushort4 u;
  u.x = f2bf(v[0]); u.y = f2bf(v[1]); u.z = f2bf(v[2]); u.w = f2bf(v[3]);
  reinterpret_cast<ushort4*>(out)[i] = u;
}

// ---------------- transpose + convert: W[K][N] fp32 -> Wt[N][K] bf16 --------
__global__ __launch_bounds__(256) void k_tr(const float* __restrict__ W,
                                            ushort* __restrict__ Wt,
                                            int K, int N) {
  __shared__ float tile[32][36];
  int t = threadIdx.x;
  int n0 = blockIdx.x * 32, k0 = blockIdx.y * 32;
  int lr = t >> 3, lc = (t & 7) * 4;
  *(f4v*)&tile[lr][lc] = *(const f4v*)&W[(size_t)(k0 + lr) * N + n0 + lc];
  __syncthreads();
  int sn = t >> 3, sk = (t & 7) * 4;
  ushort4 u;
  u.x = f2bf(tile[sk + 0][sn]);
  u.y = f2bf(tile[sk + 1][sn]);
  u.z = f2bf(tile[sk + 2][sn]);
  u.w = f2bf(tile[sk + 3][sn]);
  *(ushort4*)&Wt[(size_t)(n0 + sn) * K + k0 + sk] = u;
}

// ---------------- 256x256 deep-pipelined bf16 MFMA GEMM ---------------------
// C = A[M][K] * Bt[N][K]^T (+bias/gelu). 8 waves (2M x 4N), BK=32, ring-4 LDS
// (128 KiB), prefetch distance 3, counted s_waitcnt vmcnt(8) at tile
// boundaries (loads stay in flight across raw s_barrier — never drained to 0
// in the main loop). LDS layout: rows of 32 shorts (64B); 16B chunk c of row
// r holds global chunk c ^ ((r>>1)&3) (pre-swizzled global source, swizzled
// ds_read -> 2-way bank aliasing = free).
// Invariant at start of tile t: t's data landed; t+1,t+2 in flight (8 loads).
// During t: issue t+3 (4 loads) -> 12 outstanding; boundary vmcnt(8) drains
// t+1's 4 before the barrier. Buffer (t+3)&3 == (t-1)&3 was freed at the
// end-of-(t-1) barrier, so the async LDS writes cannot race any reader.
#define GBM 256
#define GBN 256
#define GBK 32
#define TILE_SH (GBM * GBK)  // 8192 shorts = 16 KiB per matrix per buffer

__global__ __launch_bounds__(512, 2) void k_gemm256(
    const ushort* __restrict__ A, const ushort* __restrict__ Bt,
    const float* __restrict__ bias, float* __restrict__ Cf,
    ushort* __restrict__ Cb, int M, int N, int K, int gelu) {
  __shared__ ushort As[4 * TILE_SH];
  __shared__ ushort Bs[4 * TILE_SH];
  const int m0 = blockIdx.y * GBM, n0 = blockIdx.x * GBN;
  const int t = threadIdx.x;
  const int w = t >> 6, lane = t & 63;
  const int quad = lane >> 4, l16 = lane & 15;
  const int wm = (w >> 2) * 128, wn = (w & 3) * 64;
  const int kchunk = K / gridDim.z;
  const int kbeg = blockIdx.z * kchunk;
  const int NT = kchunk / GBK;  // >= 16 for all launches here
  if (Cf && gridDim.z > 1) Cf += (size_t)blockIdx.z * M * N;

  // staging: per wave 32 rows, 2 issues x 16 rows; lane -> (row srow, chunk)
  const int srow = lane >> 2;                     // 0..15
  const int cg = (lane & 3) ^ ((srow >> 1) & 3);  // pre-swizzled global chunk
  const ushort* gA = A + (size_t)(m0 + w * 32 + srow) * K + kbeg + cg * 8;
  const ushort* gB = Bt + (size_t)(n0 + w * 32 + srow) * K + kbeg + cg * 8;
  // ds_read bases (shorts): chunk = quad ^ ((row>>1)&3) == quad ^ ((l16>>1)&3)
  const int swz = (quad ^ ((l16 >> 1) & 3)) * 8;
  const int baseA = (wm + l16) * GBK + swz;
  const int baseB = (wn + l16) * GBK + swz;

  f4v acc[8][4] = {};

  // prologue: stage tiles 0,1,2 (12 loads); vmcnt(8) -> tile 0 landed
#pragma unroll
  for (int pt = 0; pt < 3; ++pt) {
    ushort* lA = &As[pt * TILE_SH + (w * 32) * GBK];
    ushort* lB = &Bs[pt * TILE_SH + (w * 32) * GBK];
    load16_lds(gA + pt * GBK, lA);
    load16_lds(gA + pt * GBK + (size_t)16 * K, lA + 16 * GBK);
    load16_lds(gB + pt * GBK, lB);
    load16_lds(gB + pt * GBK + (size_t)16 * K, lB + 16 * GBK);
  }
  asm volatile("s_waitcnt vmcnt(8)\n\ts_barrier" ::: "memory");

  for (int tt = 0; tt < NT; ++tt) {
    const ushort* At = &As[(tt & 3) * TILE_SH];
    const ushort* Bc = &Bs[(tt & 3) * TILE_SH];
    const int nb = (tt + 3) & 3;
    // ---- phase 1: A frags + B0,B1; issue next A half; MFMA j=0,1 ----
    s8v a[8], b0, b1;
#pragma unroll
    for (int i = 0; i < 8; ++i)
      a[i] = *(const s8v*)&At[baseA + i * 16 * GBK];
    b0 = *(const s8v*)&Bc[baseB + 0 * 16 * GBK];
    b1 = *(const s8v*)&Bc[baseB + 1 * 16 * GBK];
    if (tt + 3 < NT) {
      ushort* lA = &As[nb * TILE_SH + (w * 32) * GBK];
      load16_lds(gA + (size_t)(tt + 3) * GBK, lA);
      load16_lds(gA + (size_t)(tt + 3) * GBK + (size_t)16 * K, lA + 16 * GBK);
    }
    __builtin_amdgcn_s_setprio(1);
#pragma unroll
    for (int i = 0; i < 8; ++i) {
      acc[i][0] = __builtin_amdgcn_mfma_f32_16x16x32_bf16(a[i], b0, acc[i][0], 0, 0, 0);
      acc[i][1] = __builtin_amdgcn_mfma_f32_16x16x32_bf16(a[i], b1, acc[i][1], 0, 0, 0);
    }
    __builtin_amdgcn_s_setprio(0);
    asm volatile("s_barrier" ::: "memory");
    // ---- phase 2: B2,B3; issue next B half; MFMA j=2,3 ----
    s8v b2 = *(const s8v*)&Bc[baseB + 2 * 16 * GBK];
    s8v b3 = *(const s8v*)&Bc[baseB + 3 * 16 * GBK];
    if (tt + 3 < NT) {
      ushort* lB = &Bs[nb * TILE_SH + (w * 32) * GBK];
      load16_lds(gB + (size_t)(tt + 3) * GBK, lB);
      load16_lds(gB + (size_t)(tt + 3) * GBK + (size_t)16 * K, lB + 16 * GBK);
    }
    __builtin_amdgcn_s_setprio(1);
#pragma unroll
    for (int i = 0; i < 8; ++i) {
      acc[i][2] = __builtin_amdgcn_mfma_f32_16x16x32_bf16(a[i], b2, acc[i][2], 0, 0, 0);
      acc[i][3] = __builtin_amdgcn_mfma_f32_16x16x32_bf16(a[i], b3, acc[i][3], 0, 0, 0);
    }
    __builtin_amdgcn_s_setprio(0);
    // ---- boundary: counted vmcnt, never 0 until the pipe drains ----
    if (tt + 4 <= NT) {
      asm volatile("s_waitcnt vmcnt(8)\n\ts_barrier" ::: "memory");
    } else if (tt + 3 <= NT) {
      asm volatile("s_waitcnt vmcnt(4)\n\ts_barrier" ::: "memory");
    } else if (tt + 2 <= NT) {
      asm volatile("s_waitcnt vmcnt(0)\n\ts_barrier" ::: "memory");
    }
  }

  // epilogue: per wave 128x64 output
#pragma unroll
  for (int i = 0; i < 8; ++i) {
    int rbase = m0 + wm + i * 16 + quad * 4;
#pragma unroll
    for (int j = 0; j < 4; ++j) {
      int cidx = n0 + wn + j * 16 + l16;
      float b = bias ? bias[cidx] : 0.0f;
#pragma unroll
      for (int r = 0; r < 4; ++r) {
        float v = acc[i][j][r] + b;
        if (gelu) v = 0.5f * v * (1.0f + erff(v * 0.70710678118654752f));
        if (Cf) Cf[(size_t)(rbase + r) * N + cidx] = v;
        if (Cb) Cb[(size_t)(rbase + r) * N + cidx] = f2bf(v);
      }
    }
  }
}

// ---------------- MFMA flash attention (bf16 in/out, fp32 softmax) ----------
__global__ __launch_bounds__(256) void k_attn_mfma(const ushort* __restrict__ qkv,
                                                   ushort* __restrict__ ctx) {
  __shared__ ushort Ks[64][136];
  __shared__ ushort Vt[128][72];
  __shared__ ushort Ps[4][16][72];
  const int idx = blockIdx.x;
  const int h = idx & (NH - 1);
  const int qt = (SEQ / 64 - 1) - (idx >> 4);
  const int q0 = qt * 64;
  const int t = threadIdx.x;
  const int wave = t >> 6, lane = t & 63;
  const int quad = lane >> 4, l16 = lane & 15;
  const float scale = 0.022097086912079608f;  // 1/sqrt(2048)

  s8v aq[4];
  {
    const ushort* qp = qkv + (size_t)(q0 + 16 * wave + l16) * (3 * DM) + h * HD + quad * 8;
#pragma unroll
    for (int ks = 0; ks < 4; ++ks)
      aq[ks] = *(const s8v*)(qp + ks * 32);
  }
  f4v acc_o[8] = {};
  float m_r[4], l_r[4];
#pragma unroll
  for (int r = 0; r < 4; ++r) { m_r[r] = -1e30f; l_r[r] = 0.0f; }

  for (int kt = 0; kt <= qt; ++kt) {
    const int k0 = kt * 64;
    __syncthreads();
    {
      const ushort* kp = qkv + (size_t)k0 * (3 * DM) + DM + h * HD;
#pragma unroll
      for (int i = 0; i < 4; ++i) {
        int ch = t + i * 256;
        int row = ch >> 4, c8 = (ch & 15) * 8;
        *(s8v*)&Ks[row][c8] = *(const s8v*)(kp + (size_t)row * (3 * DM) + c8);
      }
      const ushort* vp = qkv + (size_t)k0 * (3 * DM) + 2 * DM + h * HD;
#pragma unroll
      for (int i = 0; i < 4; ++i) {
        int id = t + i * 256;
        int d = id & 127, sg = id >> 7;
        ushort e0 = vp[(size_t)(sg * 8 + 0) * (3 * DM) + d];
        ushort e1 = vp[(size_t)(sg * 8 + 1) * (3 * DM) + d];
        ushort e2 = vp[(size_t)(sg * 8 + 2) * (3 * DM) + d];
        ushort e3 = vp[(size_t)(sg * 8 + 3) * (3 * DM) + d];
        ushort e4 = vp[(size_t)(sg * 8 + 4) * (3 * DM) + d];
        ushort e5 = vp[(size_t)(sg * 8 + 5) * (3 * DM) + d];
        ushort e6 = vp[(size_t)(sg * 8 + 6) * (3 * DM) + d];
        ushort e7 = vp[(size_t)(sg * 8 + 7) * (3 * DM) + d];
        uint4 pk;
        pk.x = (uint)e0 | ((uint)e1 << 16);
        pk.y = (uint)e2 | ((uint)e3 << 16);
        pk.z = (uint)e4 | ((uint)e5 << 16);
        pk.w = (uint)e6 | ((uint)e7 << 16);
        *(uint4*)&Vt[d][sg * 8] = pk;
      }
    }
    __syncthreads();

    f4v sacc[4] = {};
#pragma unroll
    for (int ks = 0; ks < 4; ++ks) {
      s8v bk[4];
#pragma unroll
      for (int j = 0; j < 4; ++j)
        bk[j] = *(const s8v*)&Ks[j * 16 + l16][ks * 32 + quad * 8];
#pragma unroll
      for (int j = 0; j < 4; ++j)
        sacc[j] = __builtin_amdgcn_mfma_f32_16x16x32_bf16(aq[ks], bk[j], sacc[j], 0, 0, 0);
    }
    if (kt == qt) {
#pragma unroll
      for (int j = 0; j < 4; ++j)
#pragma unroll
        for (int r = 0; r < 4; ++r) {
          int lrow = 16 * wave + quad * 4 + r;
          int lcol = j * 16 + l16;
          sacc[j][r] = (lcol > lrow) ? -1e30f : sacc[j][r] * scale;
        }
    } else {
#pragma unroll
      for (int j = 0; j < 4; ++j)
#pragma unroll
        for (int r = 0; r < 4; ++r) sacc[j][r] *= scale;
    }
    float alpha[4];
#pragma unroll
    for (int r = 0; r < 4; ++r) {
      float mx = fmaxf(fmaxf(sacc[0][r], sacc[1][r]), fmaxf(sacc[2][r], sacc[3][r]));
      mx = fmaxf(mx, __shfl_xor(mx, 1));
      mx = fmaxf(mx, __shfl_xor(mx, 2));
      mx = fmaxf(mx, __shfl_xor(mx, 4));
      mx = fmaxf(mx, __shfl_xor(mx, 8));
      float mn = fmaxf(m_r[r], mx);
      alpha[r] = __expf(m_r[r] - mn);
      m_r[r] = mn;
      float ps = 0.0f;
#pragma unroll
      for (int j = 0; j < 4; ++j) {
        float p = __expf(sacc[j][r] - mn);
        sacc[j][r] = p;
        ps += p;
      }
      ps += __shfl_xor(ps, 1);
      ps += __shfl_xor(ps, 2);
      ps += __shfl_xor(ps, 4);
      ps += __shfl_xor(ps, 8);
      l_r[r] = l_r[r] * alpha[r] + ps;
    }
#pragma unroll
    for (int j = 0; j < 4; ++j)
#pragma unroll
      for (int r = 0; r < 4; ++r)
        Ps[wave][quad * 4 + r][j * 16 + l16] = f2bf(sacc[j][r]);
#pragma unroll
    for (int nd = 0; nd < 8; ++nd)
#pragma unroll
      for (int r = 0; r < 4; ++r) acc_o[nd][r] *= alpha[r];
#pragma unroll
    for (int ks2 = 0; ks2 < 2; ++ks2) {
      s8v ap = *(const s8v*)&Ps[wave][l16][ks2 * 32 + quad * 8];
#pragma unroll
      for (int nd = 0; nd < 8; ++nd) {
        s8v bv = *(const s8v*)&Vt[nd * 16 + l16][ks2 * 32 + quad * 8];
        acc_o[nd] = __builtin_amdgcn_mfma_f32_16x16x32_bf16(ap, bv, acc_o[nd], 0, 0, 0);
      }
    }
  }
  float rl[4];
#pragma unroll
  for (int r = 0; r < 4; ++r) rl[r] = 1.0f / l_r[r];
#pragma unroll
  for (int nd = 0; nd < 8; ++nd) {
    int col = h * HD + nd * 16 + l16;
#pragma unroll
    for (int r = 0; r < 4; ++r) {
      int row = q0 + 16 * wave + quad * 4 + r;
      ctx[(size_t)row * DM + col] = f2bf(acc_o[nd][r] * rl[r]);
    }
  }
}

// -------- layernorm(A + sum(partials) + bias): fp32 out + optional bf16 ----
__global__ __launch_bounds__(256) void k_ln_sk(const float* __restrict__ A,
                                               const float* __restrict__ P, int np,
                                               const float* __restrict__ bias,
                                               const float* __restrict__ g,
                                               const float* __restrict__ be,
                                               float* __restrict__ outf,
                                               ushort* __restrict__ outb) {
  int row = blockIdx.x;
  int t = threadIdx.x;
  const f4v* av = reinterpret_cast<const f4v*>(A + (size_t)row * DM);
  f4v x0 = av[t];
  f4v x1 = av[t + 256];
  for (int s = 0; s < np; ++s) {
    const f4v* pv = reinterpret_cast<const f4v*>(P + (size_t)s * SEQ * DM + (size_t)row * DM);
    x0 += pv[t];
    x1 += pv[t + 256];
  }
  const f4v* bb = reinterpret_cast<const f4v*>(bias);
  x0 += bb[t];
  x1 += bb[t + 256];
  float s = x0[0] + x0[1] + x0[2] + x0[3] + x1[0] + x1[1] + x1[2] + x1[3];
  float q = x0[0]*x0[0] + x0[1]*x0[1] + x0[2]*x0[2] + x0[3]*x0[3]
          + x1[0]*x1[0] + x1[1]*x1[1] + x1[2]*x1[2] + x1[3]*x1[3];
#pragma unroll
  for (int off = 32; off; off >>= 1) {
    s += __shfl_down(s, off, 64);
    q += __shfl_down(q, off, 64);
  }
  __shared__ float rs[4], rq[4];
  if ((t & 63) == 0) { rs[t >> 6] = s; rq[t >> 6] = q; }
  __syncthreads();
  s = rs[0] + rs[1] + rs[2] + rs[3];
  q = rq[0] + rq[1] + rq[2] + rq[3];
  float mu = s * (1.0f / DM);
  float var = q * (1.0f / DM) - mu * mu;
  float rstd = rsqrtf(var + 1e-5f);
  const f4v* gv = reinterpret_cast<const f4v*>(g);
  const f4v* bev = reinterpret_cast<const f4v*>(be);
  f4v y0 = (x0 - mu) * rstd * gv[t] + bev[t];
  f4v y1 = (x1 - mu) * rstd * gv[t + 256] + bev[t + 256];
  reinterpret_cast<f4v*>(outf + (size_t)row * DM)[t] = y0;
  reinterpret_cast<f4v*>(outf + (size_t)row * DM)[t + 256] = y1;
  if (outb) {
    ushort4 u0, u1;
    u0.x = f2bf(y0[0]); u0.y = f2bf(y0[1]); u0.z = f2bf(y0[2]); u0.w = f2bf(y0[3]);
    u1.x = f2bf(y1[0]); u1.y = f2bf(y1[1]); u1.z = f2bf(y1[2]); u1.w = f2bf(y1[3]);
    reinterpret_cast<ushort4*>(outb + (size_t)row * DM)[t] = u0;
    reinterpret_cast<ushort4*>(outb + (size_t)row * DM)[t + 256] = u1;
  }
}

extern "C" void kernel_launch(void* const* d_in, const int* in_sizes, int n_in,
                              void* d_out, int out_size, void* d_ws, size_t ws_size,
                              hipStream_t stream) {
  const float* x     = (const float*)d_in[0];
  const float* C_w   = (const float*)d_in[1];
  const float* C_b   = (const float*)d_in[2];
  const float* lin_w = (const float*)d_in[3];
  const float* lin_b = (const float*)d_in[4];
  const float* ff1_w = (const float*)d_in[5];
  const float* ff1_b = (const float*)d_in[6];
  const float* ff2_w = (const float*)d_in[7];
  const float* ff2_b = (const float*)d_in[8];
  const float* ln1g  = (const float*)d_in[9];
  const float* ln1b  = (const float*)d_in[10];
  const float* ln2g  = (const float*)d_in[11];
  const float* ln2b  = (const float*)d_in[12];

  char* ws = (char*)d_ws;
  size_t off = 0;
  auto take = [&](size_t bytes) {
    char* p = ws + off;
    off += (bytes + 255) & ~(size_t)255;
    return p;
  };
  ushort* Wt   = (ushort*)take((size_t)FF * DM * 2);      // 33.6 MB
  ushort* qkvb = (ushort*)take((size_t)SEQ * 3 * DM * 2); // 25.2 MB
  ushort* xb   = (ushort*)take((size_t)SEQ * DM * 2);     //  8.4 MB
  ushort* ctxb = (ushort*)take((size_t)SEQ * DM * 2);     //  8.4 MB
  ushort* bigb = (ushort*)take((size_t)SEQ * FF * 2);     // 33.6 MB
  float*  h1   = (float*) take((size_t)SEQ * DM * 4);     // 16.8 MB
  float*  part = (float*) take((size_t)4 * SEQ * DM * 4); // 67.1 MB split-K partials

  k_cvt<<<SEQ * DM / 1024, 256, 0, stream>>>(x, xb, SEQ * DM / 4);
  // qkv = x @ C_w + C_b (bf16 out)
  k_tr<<<dim3(3 * DM / 32, DM / 32), 256, 0, stream>>>(C_w, Wt, DM, 3 * DM);
  k_gemm256<<<dim3(3 * DM / 256, SEQ / 256, 1), 512, 0, stream>>>(xb, Wt, C_b, nullptr, qkvb, SEQ, 3 * DM, DM, 0);
  // causal MFMA flash attention -> ctxb (bf16)
  k_attn_mfma<<<dim3((SEQ / 64) * NH), 256, 0, stream>>>(qkvb, ctxb);
  // proj partials: ctx @ lin_w, split-K=4 (bias folded into LN1)
  k_tr<<<dim3(DM / 32, DM / 32), 256, 0, stream>>>(lin_w, Wt, DM, DM);
  k_gemm256<<<dim3(DM / 256, SEQ / 256, 4), 512, 0, stream>>>(ctxb, Wt, nullptr, part, nullptr, SEQ, DM, DM, 0);
  // h1 = LN(x + sum(part) + lin_b); bf16 copy -> xb
  k_ln_sk<<<SEQ, 256, 0, stream>>>(x, part, 4, lin_b, ln1g, ln1b, h1, xb);
  // ff1 = gelu(h1 @ ff1_w + ff1_b) (bf16 out)
  k_tr<<<dim3(FF / 32, DM / 32), 256, 0, stream>>>(ff1_w, Wt, DM, FF);
  k_gemm256<<<dim3(FF / 256, SEQ / 256, 1), 512, 0, stream>>>(xb, Wt, ff1_b, nullptr, bigb, SEQ, FF, DM, 1);
  // ff2 partials: gelu(ff1) @ ff2_w, split-K=4 (bias folded into LN2)
  k_tr<<<dim3(DM / 32, FF / 32), 256, 0, stream>>>(ff2_w, Wt, FF, DM);
  k_gemm256<<<dim3(DM / 256, SEQ / 256, 4), 512, 0, stream>>>(bigb, Wt, nullptr, part, nullptr, SEQ, DM, FF, 0);
  // out = LN(h1 + sum(part) + ff2_b)
  k_ln_sk<<<SEQ, 256, 0, stream>>>(h1, part, 4, ff2_b, ln2g, ln2b, (float*)d_out, (ushort*)nullptr);
}